// Round 1
// baseline (2171.410 us; speedup 1.0000x reference)
//
#include <hip/hip_runtime.h>
#include <cstdint>
#include <cstddef>

#define NN 10000
#define NE 320000
#define TT 24
#define HD 64
#define G4 256   // 4*H

__device__ __forceinline__ float sigm(float x){ return 1.0f/(1.0f + __expf(-x)); }
__device__ __forceinline__ float tanh_fast(float x){ return 2.0f/(1.0f + __expf(-2.0f*x)) - 1.0f; }

// ---- setup: degrees ----
__global__ __launch_bounds__(256) void degree_kernel(const int* __restrict__ esrc, const int* __restrict__ edst,
                                                     int* __restrict__ deg_out, int* __restrict__ deg_in){
  int e = blockIdx.x*256 + threadIdx.x;
  if (e < NE){
    atomicAdd(&deg_out[esrc[e]], 1);
    atomicAdd(&deg_in[edst[e]], 1);
  }
}

// ---- setup: symmetric norms ----
__global__ __launch_bounds__(256) void norm_kernel(const int* __restrict__ deg_out, const int* __restrict__ deg_in,
                                                   float* __restrict__ norm_src, float* __restrict__ norm_dst){
  int i = blockIdx.x*256 + threadIdx.x;
  if (i < NN){
    int a = deg_out[i]; norm_src[i] = (a>0) ? rsqrtf((float)a) : 0.0f;
    int b = deg_in[i];  norm_dst[i] = (b>0) ? rsqrtf((float)b) : 0.0f;
  }
}

// ---- setup: exclusive prefix sum over in-degrees (single block) ----
__global__ __launch_bounds__(256) void scan_kernel(const int* __restrict__ deg_in, int* __restrict__ csr_off,
                                                   int* __restrict__ cursor){
  __shared__ int sums[256];
  const int CH = (NN + 255)/256;   // 40 elements per thread
  int tid = threadIdx.x;
  int beg = tid*CH; if (beg > NN) beg = NN;
  int end = beg+CH; if (end > NN) end = NN;
  int s = 0;
  for (int i=beg;i<end;i++) s += deg_in[i];
  sums[tid] = s;
  __syncthreads();
  if (tid == 0){
    int run = 0;
    for (int i=0;i<256;i++){ int v = sums[i]; sums[i] = run; run += v; }
  }
  __syncthreads();
  int run = sums[tid];
  for (int i=beg;i<end;i++){ csr_off[i] = run; cursor[i] = run; run += deg_in[i]; }
  if (tid == 0) csr_off[NN] = NE;
}

// ---- setup: CSR fill (counting sort by dst), fold norm_src into edge weight ----
__global__ __launch_bounds__(256) void fill_kernel(const int* __restrict__ esrc, const int* __restrict__ edst,
                                                   int* __restrict__ cursor, int* __restrict__ csr_src,
                                                   float* __restrict__ csr_w, const float* __restrict__ norm_src){
  int e = blockIdx.x*256 + threadIdx.x;
  if (e < NE){
    int d = edst[e]; int s = esrc[e];
    int pos = atomicAdd(&cursor[d], 1);
    csr_src[pos] = s;
    csr_w[pos]   = norm_src[s];
  }
}

// ---- phase A: per-node LSTM over all 24 steps, weights resident in registers ----
// block = 256 threads = one node; thread g owns gate row g (64 weights in VGPRs).
// h (64 floats) broadcast through LDS each step; only wave 0 (g<64) carries c and h.
__global__ __launch_bounds__(256) void lstm_kernel(const float* __restrict__ blob, const float* __restrict__ W_ih,
                                                   const float* __restrict__ b_ih, const float* __restrict__ W_hh,
                                                   const float* __restrict__ b_hh, float* __restrict__ h_all){
  const int n = blockIdx.x;
  const int g = threadIdx.x;
  __shared__ float lh[HD];
  __shared__ float lg[G4];

  float4 w4[16];
  const float4* wp = reinterpret_cast<const float4*>(W_hh + (size_t)n*(G4*HD) + (size_t)g*HD);
  #pragma unroll
  for (int i=0;i<16;i++) w4[i] = wp[i];

  const float wx = W_ih[(size_t)n*G4 + g];
  const float bs = b_ih[(size_t)n*G4 + g] + b_hh[(size_t)n*G4 + g];

  float c = 0.0f;
  if (g < HD) lh[g] = 0.0f;
  __syncthreads();

  for (int t=0;t<TT;t++){
    float xt = blob[n*TT + t];
    float gate = fmaf(wx, xt, bs);
    const float4* h4 = reinterpret_cast<const float4*>(lh);
    #pragma unroll
    for (int i=0;i<16;i++){
      float4 hv = h4[i];
      gate = fmaf(hv.x, w4[i].x, gate);
      gate = fmaf(hv.y, w4[i].y, gate);
      gate = fmaf(hv.z, w4[i].z, gate);
      gate = fmaf(hv.w, w4[i].w, gate);
    }
    lg[g] = gate;
    __syncthreads();
    if (g < HD){
      float iv = sigm(lg[g]);
      float fv = sigm(lg[HD+g]);
      float gv = tanh_fast(lg[2*HD+g]);
      float ov = sigm(lg[3*HD+g]);
      c = fmaf(fv, c, iv*gv);
      float h = ov * tanh_fast(c);
      lh[g] = h;
      h_all[(size_t)t*(NN*HD) + (size_t)n*HD + g] = h;
    }
    __syncthreads();
  }
}

// ---- phase B: gconv layer (gather over CSR, then 64x64 GEMV epilogue, relu) ----
// wave per (t,n); lane = output channel; W column resident in 64 VGPRs.
__global__ __launch_bounds__(256) void gconv_mid_kernel(const float* __restrict__ src_feat, float* __restrict__ dst_feat,
                                                        const float* __restrict__ Wg, const float* __restrict__ bg,
                                                        const int* __restrict__ csr_off, const int* __restrict__ csr_src,
                                                        const float* __restrict__ csr_w, const float* __restrict__ norm_dst){
  int wid = blockIdx.x*4 + (threadIdx.x >> 6);
  int lane = threadIdx.x & 63;
  if (wid >= TT*NN) return;
  int t = wid / NN;
  int n = wid - t*NN;

  float wcol[HD];
  #pragma unroll
  for (int k=0;k<HD;k++) wcol[k] = Wg[k*HD + lane];

  const float* base = src_feat + (size_t)t*(NN*HD);
  int e = csr_off[n];
  const int end = csr_off[n+1];
  float a0 = 0.f, a1 = 0.f;
  for (; e+1 < end; e += 2){
    int s0 = csr_src[e], s1 = csr_src[e+1];
    float w0 = csr_w[e], w1 = csr_w[e+1];
    a0 = fmaf(w0, base[s0*HD + lane], a0);
    a1 = fmaf(w1, base[s1*HD + lane], a1);
  }
  if (e < end) a0 = fmaf(csr_w[e], base[csr_src[e]*HD + lane], a0);
  float acc = (a0 + a1) * norm_dst[n];

  float out = bg[lane];
  #pragma unroll
  for (int k=0;k<HD;k++){
    float ak = __shfl(acc, k, 64);
    out = fmaf(ak, wcol[k], out);
  }
  out = fmaxf(out, 0.0f);
  dst_feat[(size_t)t*(NN*HD) + (size_t)n*HD + lane] = out;
}

// ---- phase B: last hidden gconv fused with the 64->1 projection:
// q[t,n] = norm_src[n] * ( relu(gconv2(z1)) . Wg2 )
__global__ __launch_bounds__(256) void gconv_last_kernel(const float* __restrict__ src_feat, float* __restrict__ q,
                                                         const float* __restrict__ Wg, const float* __restrict__ bg,
                                                         const float* __restrict__ Wg2,
                                                         const int* __restrict__ csr_off, const int* __restrict__ csr_src,
                                                         const float* __restrict__ csr_w, const float* __restrict__ norm_dst,
                                                         const float* __restrict__ norm_src){
  int wid = blockIdx.x*4 + (threadIdx.x >> 6);
  int lane = threadIdx.x & 63;
  if (wid >= TT*NN) return;
  int t = wid / NN;
  int n = wid - t*NN;

  float wcol[HD];
  #pragma unroll
  for (int k=0;k<HD;k++) wcol[k] = Wg[k*HD + lane];

  const float* base = src_feat + (size_t)t*(NN*HD);
  int e = csr_off[n];
  const int end = csr_off[n+1];
  float a0 = 0.f, a1 = 0.f;
  for (; e+1 < end; e += 2){
    int s0 = csr_src[e], s1 = csr_src[e+1];
    float w0 = csr_w[e], w1 = csr_w[e+1];
    a0 = fmaf(w0, base[s0*HD + lane], a0);
    a1 = fmaf(w1, base[s1*HD + lane], a1);
  }
  if (e < end) a0 = fmaf(csr_w[e], base[csr_src[e]*HD + lane], a0);
  float acc = (a0 + a1) * norm_dst[n];

  float out = bg[lane];
  #pragma unroll
  for (int k=0;k<HD;k++){
    float ak = __shfl(acc, k, 64);
    out = fmaf(ak, wcol[k], out);
  }
  out = fmaxf(out, 0.0f);

  float p = out * Wg2[lane];
  #pragma unroll
  for (int off=32; off; off >>= 1) p += __shfl_xor(p, off, 64);
  if (lane == 0) q[n*32 + t] = p * norm_src[n];
}

// ---- phase B: final scalar aggregation -> output (N,T) ----
__global__ __launch_bounds__(256) void out_kernel(const float* __restrict__ q, const int* __restrict__ csr_off,
                                                  const int* __restrict__ csr_src, const float* __restrict__ norm_dst,
                                                  const float* __restrict__ bg2, float* __restrict__ out){
  int wid = blockIdx.x*4 + (threadIdx.x >> 6);
  int lane = threadIdx.x & 63;
  if (wid >= NN) return;
  int n = wid;
  int e = csr_off[n];
  const int end = csr_off[n+1];
  if (lane < TT){
    float s = 0.0f;
    for (; e < end; e++){
      int src = csr_src[e];
      s += q[src*32 + lane];
    }
    out[n*TT + lane] = fmaf(norm_dst[n], s, bg2[0]);
  }
}

extern "C" void kernel_launch(void* const* d_in, const int* in_sizes, int n_in,
                              void* d_out, int out_size, void* d_ws, size_t ws_size,
                              hipStream_t stream) {
  (void)in_sizes; (void)n_in; (void)out_size; (void)ws_size;
  const float* blob  = (const float*)d_in[0];
  const float* W_ih  = (const float*)d_in[1];
  const float* b_ih  = (const float*)d_in[2];
  const float* W_hh  = (const float*)d_in[3];
  const float* b_hh  = (const float*)d_in[4];
  const float* Wg0   = (const float*)d_in[5];
  const float* bg0   = (const float*)d_in[6];
  const float* Wg1   = (const float*)d_in[7];
  const float* bg1   = (const float*)d_in[8];
  const float* Wg2   = (const float*)d_in[9];
  const float* bg2   = (const float*)d_in[10];
  const int* edge_src = (const int*)d_in[11];
  const int* edge_dst = (const int*)d_in[12];
  float* out = (float*)d_out;

  char* ws = (char*)d_ws;
  size_t off = 0;
  auto alloc = [&](size_t bytes)->char* {
    char* p = ws + off; off += (bytes + 255) & ~(size_t)255; return p;
  };
  float* h_all   = (float*)alloc((size_t)TT*NN*HD*sizeof(float));   // 61.44 MB
  float* z1      = (float*)alloc((size_t)TT*NN*HD*sizeof(float));   // 61.44 MB
  float* q       = (float*)alloc((size_t)NN*32*sizeof(float));      // 1.28 MB
  int*   deg_out = (int*)  alloc((size_t)NN*sizeof(int));
  int*   deg_in  = (int*)  alloc((size_t)NN*sizeof(int));
  float* norm_src= (float*)alloc((size_t)NN*sizeof(float));
  float* norm_dst= (float*)alloc((size_t)NN*sizeof(float));
  int*   csr_off = (int*)  alloc((size_t)(NN+1)*sizeof(int));
  int*   cursor  = (int*)  alloc((size_t)NN*sizeof(int));
  int*   csr_src = (int*)  alloc((size_t)NE*sizeof(int));
  float* csr_w   = (float*)alloc((size_t)NE*sizeof(float));

  hipMemsetAsync(deg_out, 0, (size_t)NN*sizeof(int), stream);
  hipMemsetAsync(deg_in,  0, (size_t)NN*sizeof(int), stream);

  degree_kernel<<<(NE+255)/256, 256, 0, stream>>>(edge_src, edge_dst, deg_out, deg_in);
  norm_kernel<<<(NN+255)/256, 256, 0, stream>>>(deg_out, deg_in, norm_src, norm_dst);
  scan_kernel<<<1, 256, 0, stream>>>(deg_in, csr_off, cursor);
  fill_kernel<<<(NE+255)/256, 256, 0, stream>>>(edge_src, edge_dst, cursor, csr_src, csr_w, norm_src);

  lstm_kernel<<<NN, 256, 0, stream>>>(blob, W_ih, b_ih, W_hh, b_hh, h_all);

  gconv_mid_kernel<<<(TT*NN)/4, 256, 0, stream>>>(h_all, z1, Wg0, bg0, csr_off, csr_src, csr_w, norm_dst);
  // z2 fused with 64->1 projection; writes q only (no z2 buffer needed)
  gconv_last_kernel<<<(TT*NN)/4, 256, 0, stream>>>(z1, q, Wg1, bg1, Wg2, csr_off, csr_src, csr_w, norm_dst, norm_src);
  out_kernel<<<(NN+3)/4, 256, 0, stream>>>(q, csr_off, csr_src, norm_dst, bg2, out);
}

// Round 2
// 1647.562 us; speedup vs baseline: 1.3180x; 1.3180x over previous
//
#include <hip/hip_runtime.h>
#include <cstdint>
#include <cstddef>

#define NN 10000
#define NE 320000
#define TT 24
#define HD 64
#define G4 256   // 4*H

__device__ __forceinline__ float sigm(float x){ return 1.0f/(1.0f + __expf(-x)); }
__device__ __forceinline__ float tanh_fast(float x){ return 2.0f/(1.0f + __expf(-2.0f*x)) - 1.0f; }

// ---- setup: degrees ----
__global__ __launch_bounds__(256) void degree_kernel(const int* __restrict__ esrc, const int* __restrict__ edst,
                                                     int* __restrict__ deg_out, int* __restrict__ deg_in){
  int e = blockIdx.x*256 + threadIdx.x;
  if (e < NE){
    atomicAdd(&deg_out[esrc[e]], 1);
    atomicAdd(&deg_in[edst[e]], 1);
  }
}

// ---- setup: symmetric norms ----
__global__ __launch_bounds__(256) void norm_kernel(const int* __restrict__ deg_out, const int* __restrict__ deg_in,
                                                   float* __restrict__ norm_src, float* __restrict__ norm_dst){
  int i = blockIdx.x*256 + threadIdx.x;
  if (i < NN){
    int a = deg_out[i]; norm_src[i] = (a>0) ? rsqrtf((float)a) : 0.0f;
    int b = deg_in[i];  norm_dst[i] = (b>0) ? rsqrtf((float)b) : 0.0f;
  }
}

// ---- setup: exclusive prefix sum over in-degrees (single block) ----
__global__ __launch_bounds__(256) void scan_kernel(const int* __restrict__ deg_in, int* __restrict__ csr_off,
                                                   int* __restrict__ cursor){
  __shared__ int sums[256];
  const int CH = (NN + 255)/256;   // 40 elements per thread
  int tid = threadIdx.x;
  int beg = tid*CH; if (beg > NN) beg = NN;
  int end = beg+CH; if (end > NN) end = NN;
  int s = 0;
  for (int i=beg;i<end;i++) s += deg_in[i];
  sums[tid] = s;
  __syncthreads();
  if (tid == 0){
    int run = 0;
    for (int i=0;i<256;i++){ int v = sums[i]; sums[i] = run; run += v; }
  }
  __syncthreads();
  int run = sums[tid];
  for (int i=beg;i<end;i++){ csr_off[i] = run; cursor[i] = run; run += deg_in[i]; }
  if (tid == 0) csr_off[NN] = NE;
}

// ---- setup: CSR fill (counting sort by dst), fold norm_src into edge weight ----
__global__ __launch_bounds__(256) void fill_kernel(const int* __restrict__ esrc, const int* __restrict__ edst,
                                                   int* __restrict__ cursor, int* __restrict__ csr_src,
                                                   float* __restrict__ csr_w, const float* __restrict__ norm_src){
  int e = blockIdx.x*256 + threadIdx.x;
  if (e < NE){
    int d = edst[e]; int s = esrc[e];
    int pos = atomicAdd(&cursor[d], 1);
    csr_src[pos] = s;
    csr_w[pos]   = norm_src[s];
  }
}

// ---- phase A: per-node LSTM over all 24 steps, weights resident in registers ----
// block = 256 threads = one node; thread g owns gate row g (64 weights in VGPRs).
// h (64 floats) broadcast through LDS each step; only wave 0 (g<64) carries c and h.
// h_all layout: [n][t][ch]  (node-major so the gconv gather reads 6KB contiguous per edge)
__global__ __launch_bounds__(256) void lstm_kernel(const float* __restrict__ blob, const float* __restrict__ W_ih,
                                                   const float* __restrict__ b_ih, const float* __restrict__ W_hh,
                                                   const float* __restrict__ b_hh, float* __restrict__ h_all){
  const int n = blockIdx.x;
  const int g = threadIdx.x;
  __shared__ float lh[HD];
  __shared__ float lg[G4];

  float4 w4[16];
  const float4* wp = reinterpret_cast<const float4*>(W_hh + (size_t)n*(G4*HD) + (size_t)g*HD);
  #pragma unroll
  for (int i=0;i<16;i++) w4[i] = wp[i];

  const float wx = W_ih[(size_t)n*G4 + g];
  const float bs = b_ih[(size_t)n*G4 + g] + b_hh[(size_t)n*G4 + g];

  float c = 0.0f;
  if (g < HD) lh[g] = 0.0f;
  __syncthreads();

  for (int t=0;t<TT;t++){
    float xt = blob[n*TT + t];
    float gate = fmaf(wx, xt, bs);
    const float4* h4 = reinterpret_cast<const float4*>(lh);
    #pragma unroll
    for (int i=0;i<16;i++){
      float4 hv = h4[i];
      gate = fmaf(hv.x, w4[i].x, gate);
      gate = fmaf(hv.y, w4[i].y, gate);
      gate = fmaf(hv.z, w4[i].z, gate);
      gate = fmaf(hv.w, w4[i].w, gate);
    }
    lg[g] = gate;
    __syncthreads();
    if (g < HD){
      float iv = sigm(lg[g]);
      float fv = sigm(lg[HD+g]);
      float gv = tanh_fast(lg[2*HD+g]);
      float ov = sigm(lg[3*HD+g]);
      c = fmaf(fv, c, iv*gv);
      float h = ov * tanh_fast(c);
      lh[g] = h;
      h_all[(size_t)n*(TT*HD) + (size_t)t*HD + g] = h;
    }
    __syncthreads();
  }
}

// ---- phase B: gconv layer, wave per NODE, all 24 timesteps batched in registers ----
// lane = output channel. acc[t] accumulates gathered features; 24-deep load pipeline per edge.
__global__ __launch_bounds__(256) void gconv_mid_kernel(const float* __restrict__ src_feat, float* __restrict__ dst_feat,
                                                        const float* __restrict__ Wg, const float* __restrict__ bg,
                                                        const int* __restrict__ csr_off, const int* __restrict__ csr_src,
                                                        const float* __restrict__ csr_w, const float* __restrict__ norm_dst){
  int n = blockIdx.x*4 + (threadIdx.x >> 6);
  int lane = threadIdx.x & 63;
  if (n >= NN) return;

  float wcol[HD];
  #pragma unroll
  for (int k=0;k<HD;k++) wcol[k] = Wg[k*HD + lane];
  float bias = bg[lane];

  float acc[TT];
  #pragma unroll
  for (int t=0;t<TT;t++) acc[t] = 0.0f;

  int e = csr_off[n];
  const int end = csr_off[n+1];
  for (; e < end; e++){
    int s = csr_src[e];
    float w = csr_w[e];
    const float* p = src_feat + (size_t)s*(TT*HD) + lane;
    float v[TT];
    #pragma unroll
    for (int t=0;t<TT;t++) v[t] = p[t*HD];
    #pragma unroll
    for (int t=0;t<TT;t++) acc[t] = fmaf(w, v[t], acc[t]);
  }
  float nd = norm_dst[n];
  #pragma unroll
  for (int t=0;t<TT;t++) acc[t] *= nd;

  float* dbase = dst_feat + (size_t)n*(TT*HD) + lane;
  #pragma unroll
  for (int t=0;t<TT;t++){
    float out = bias;
    #pragma unroll
    for (int k=0;k<HD;k++){
      float ak = __shfl(acc[t], k, 64);
      out = fmaf(ak, wcol[k], out);
    }
    out = fmaxf(out, 0.0f);
    dbase[t*HD] = out;
  }
}

// ---- phase B: last hidden gconv fused with 64->1 projection, wave per node, t-batched ----
// q[n*32+t] = norm_src[n] * ( relu(gconv(z1)[t,n,:]) . Wg2 )
__global__ __launch_bounds__(256) void gconv_last_kernel(const float* __restrict__ src_feat, float* __restrict__ q,
                                                         const float* __restrict__ Wg, const float* __restrict__ bg,
                                                         const float* __restrict__ Wg2,
                                                         const int* __restrict__ csr_off, const int* __restrict__ csr_src,
                                                         const float* __restrict__ csr_w, const float* __restrict__ norm_dst,
                                                         const float* __restrict__ norm_src){
  int n = blockIdx.x*4 + (threadIdx.x >> 6);
  int lane = threadIdx.x & 63;
  if (n >= NN) return;

  float wcol[HD];
  #pragma unroll
  for (int k=0;k<HD;k++) wcol[k] = Wg[k*HD + lane];
  float bias = bg[lane];
  float w2 = Wg2[lane];

  float acc[TT];
  #pragma unroll
  for (int t=0;t<TT;t++) acc[t] = 0.0f;

  int e = csr_off[n];
  const int end = csr_off[n+1];
  for (; e < end; e++){
    int s = csr_src[e];
    float w = csr_w[e];
    const float* p = src_feat + (size_t)s*(TT*HD) + lane;
    float v[TT];
    #pragma unroll
    for (int t=0;t<TT;t++) v[t] = p[t*HD];
    #pragma unroll
    for (int t=0;t<TT;t++) acc[t] = fmaf(w, v[t], acc[t]);
  }
  float nd = norm_dst[n];
  #pragma unroll
  for (int t=0;t<TT;t++) acc[t] *= nd;

  float ns = norm_src[n];
  #pragma unroll
  for (int t=0;t<TT;t++){
    float out = bias;
    #pragma unroll
    for (int k=0;k<HD;k++){
      float ak = __shfl(acc[t], k, 64);
      out = fmaf(ak, wcol[k], out);
    }
    out = fmaxf(out, 0.0f);
    float p2 = out * w2;
    #pragma unroll
    for (int off=32; off; off >>= 1) p2 += __shfl_xor(p2, off, 64);
    if (lane == 0) q[n*32 + t] = p2 * ns;
  }
}

// ---- phase B: final scalar aggregation -> output (N,T) ----
__global__ __launch_bounds__(256) void out_kernel(const float* __restrict__ q, const int* __restrict__ csr_off,
                                                  const int* __restrict__ csr_src, const float* __restrict__ norm_dst,
                                                  const float* __restrict__ bg2, float* __restrict__ out){
  int wid = blockIdx.x*4 + (threadIdx.x >> 6);
  int lane = threadIdx.x & 63;
  if (wid >= NN) return;
  int n = wid;
  int e = csr_off[n];
  const int end = csr_off[n+1];
  if (lane < TT){
    float s0 = 0.f, s1 = 0.f, s2 = 0.f, s3 = 0.f;
    for (; e+3 < end; e += 4){
      int a = csr_src[e], b = csr_src[e+1], c = csr_src[e+2], d = csr_src[e+3];
      s0 += q[a*32 + lane];
      s1 += q[b*32 + lane];
      s2 += q[c*32 + lane];
      s3 += q[d*32 + lane];
    }
    for (; e < end; e++) s0 += q[csr_src[e]*32 + lane];
    float s = (s0+s1)+(s2+s3);
    out[n*TT + lane] = fmaf(norm_dst[n], s, bg2[0]);
  }
}

extern "C" void kernel_launch(void* const* d_in, const int* in_sizes, int n_in,
                              void* d_out, int out_size, void* d_ws, size_t ws_size,
                              hipStream_t stream) {
  (void)in_sizes; (void)n_in; (void)out_size; (void)ws_size;
  const float* blob  = (const float*)d_in[0];
  const float* W_ih  = (const float*)d_in[1];
  const float* b_ih  = (const float*)d_in[2];
  const float* W_hh  = (const float*)d_in[3];
  const float* b_hh  = (const float*)d_in[4];
  const float* Wg0   = (const float*)d_in[5];
  const float* bg0   = (const float*)d_in[6];
  const float* Wg1   = (const float*)d_in[7];
  const float* bg1   = (const float*)d_in[8];
  const float* Wg2   = (const float*)d_in[9];
  const float* bg2   = (const float*)d_in[10];
  const int* edge_src = (const int*)d_in[11];
  const int* edge_dst = (const int*)d_in[12];
  float* out = (float*)d_out;

  char* ws = (char*)d_ws;
  size_t off = 0;
  auto alloc = [&](size_t bytes)->char* {
    char* p = ws + off; off += (bytes + 255) & ~(size_t)255; return p;
  };
  float* h_all   = (float*)alloc((size_t)TT*NN*HD*sizeof(float));   // 61.44 MB, [n][t][ch]
  float* z1      = (float*)alloc((size_t)TT*NN*HD*sizeof(float));   // 61.44 MB, [n][t][ch]
  float* q       = (float*)alloc((size_t)NN*32*sizeof(float));      // 1.28 MB
  int*   deg_out = (int*)  alloc((size_t)NN*sizeof(int));
  int*   deg_in  = (int*)  alloc((size_t)NN*sizeof(int));
  float* norm_src= (float*)alloc((size_t)NN*sizeof(float));
  float* norm_dst= (float*)alloc((size_t)NN*sizeof(float));
  int*   csr_off = (int*)  alloc((size_t)(NN+1)*sizeof(int));
  int*   cursor  = (int*)  alloc((size_t)NN*sizeof(int));
  int*   csr_src = (int*)  alloc((size_t)NE*sizeof(int));
  float* csr_w   = (float*)alloc((size_t)NE*sizeof(float));

  hipMemsetAsync(deg_out, 0, (size_t)NN*sizeof(int), stream);
  hipMemsetAsync(deg_in,  0, (size_t)NN*sizeof(int), stream);

  degree_kernel<<<(NE+255)/256, 256, 0, stream>>>(edge_src, edge_dst, deg_out, deg_in);
  norm_kernel<<<(NN+255)/256, 256, 0, stream>>>(deg_out, deg_in, norm_src, norm_dst);
  scan_kernel<<<1, 256, 0, stream>>>(deg_in, csr_off, cursor);
  fill_kernel<<<(NE+255)/256, 256, 0, stream>>>(edge_src, edge_dst, cursor, csr_src, csr_w, norm_src);

  lstm_kernel<<<NN, 256, 0, stream>>>(blob, W_ih, b_ih, W_hh, b_hh, h_all);

  gconv_mid_kernel<<<(NN+3)/4, 256, 0, stream>>>(h_all, z1, Wg0, bg0, csr_off, csr_src, csr_w, norm_dst);
  gconv_last_kernel<<<(NN+3)/4, 256, 0, stream>>>(z1, q, Wg1, bg1, Wg2, csr_off, csr_src, csr_w, norm_dst, norm_src);
  out_kernel<<<(NN+3)/4, 256, 0, stream>>>(q, csr_off, csr_src, norm_dst, bg2, out);
}

// Round 3
// 1413.613 us; speedup vs baseline: 1.5361x; 1.1655x over previous
//
#include <hip/hip_runtime.h>
#include <hip/hip_fp16.h>
#include <cstdint>
#include <cstddef>

#define NN 10000
#define NE 320000
#define TT 24
#define TP 12    // t-pairs (half2 packed)
#define HD 64
#define G4 256   // 4*H

__device__ __forceinline__ float sigm(float x){ return 1.0f/(1.0f + __expf(-x)); }
__device__ __forceinline__ float tanh_fast(float x){ return 2.0f/(1.0f + __expf(-2.0f*x)) - 1.0f; }

// ---- setup: degrees ----
__global__ __launch_bounds__(256) void degree_kernel(const int* __restrict__ esrc, const int* __restrict__ edst,
                                                     int* __restrict__ deg_out, int* __restrict__ deg_in){
  int e = blockIdx.x*256 + threadIdx.x;
  if (e < NE){
    atomicAdd(&deg_out[esrc[e]], 1);
    atomicAdd(&deg_in[edst[e]], 1);
  }
}

// ---- setup: symmetric norms ----
__global__ __launch_bounds__(256) void norm_kernel(const int* __restrict__ deg_out, const int* __restrict__ deg_in,
                                                   float* __restrict__ norm_src, float* __restrict__ norm_dst){
  int i = blockIdx.x*256 + threadIdx.x;
  if (i < NN){
    int a = deg_out[i]; norm_src[i] = (a>0) ? rsqrtf((float)a) : 0.0f;
    int b = deg_in[i];  norm_dst[i] = (b>0) ? rsqrtf((float)b) : 0.0f;
  }
}

// ---- setup: exclusive prefix sum over in-degrees (single block) ----
__global__ __launch_bounds__(256) void scan_kernel(const int* __restrict__ deg_in, int* __restrict__ csr_off,
                                                   int* __restrict__ cursor){
  __shared__ int sums[256];
  const int CH = (NN + 255)/256;
  int tid = threadIdx.x;
  int beg = tid*CH; if (beg > NN) beg = NN;
  int end = beg+CH; if (end > NN) end = NN;
  int s = 0;
  for (int i=beg;i<end;i++) s += deg_in[i];
  sums[tid] = s;
  __syncthreads();
  if (tid == 0){
    int run = 0;
    for (int i=0;i<256;i++){ int v = sums[i]; sums[i] = run; run += v; }
  }
  __syncthreads();
  int run = sums[tid];
  for (int i=beg;i<end;i++){ csr_off[i] = run; cursor[i] = run; run += deg_in[i]; }
  if (tid == 0) csr_off[NN] = NE;
}

// ---- setup: CSR fill (counting sort by dst), pack (src, norm_src[src]) as int2 ----
__global__ __launch_bounds__(256) void fill_kernel(const int* __restrict__ esrc, const int* __restrict__ edst,
                                                   int* __restrict__ cursor, int2* __restrict__ csr_pk,
                                                   const float* __restrict__ norm_src){
  int e = blockIdx.x*256 + threadIdx.x;
  if (e < NE){
    int d = edst[e]; int s = esrc[e];
    int pos = atomicAdd(&cursor[d], 1);
    csr_pk[pos] = make_int2(s, __float_as_int(norm_src[s]));
  }
}

// ---- phase A: per-node LSTM, weights in registers; writes h_all fp16 [n][tp][ch](half2 t-pairs) ----
__global__ __launch_bounds__(256) void lstm_kernel(const float* __restrict__ blob, const float* __restrict__ W_ih,
                                                   const float* __restrict__ b_ih, const float* __restrict__ W_hh,
                                                   const float* __restrict__ b_hh, __half* __restrict__ h_all){
  const int n = blockIdx.x;
  const int g = threadIdx.x;
  __shared__ float lh[HD];
  __shared__ float lg[G4];

  float4 w4[16];
  const float4* wp = reinterpret_cast<const float4*>(W_hh + (size_t)n*(G4*HD) + (size_t)g*HD);
  #pragma unroll
  for (int i=0;i<16;i++) w4[i] = wp[i];

  const float wx = W_ih[(size_t)n*G4 + g];
  const float bs = b_ih[(size_t)n*G4 + g] + b_hh[(size_t)n*G4 + g];

  float c = 0.0f;
  if (g < HD) lh[g] = 0.0f;
  __syncthreads();

  for (int t=0;t<TT;t++){
    float xt = blob[n*TT + t];
    float gate = fmaf(wx, xt, bs);
    const float4* h4 = reinterpret_cast<const float4*>(lh);
    #pragma unroll
    for (int i=0;i<16;i++){
      float4 hv = h4[i];
      gate = fmaf(hv.x, w4[i].x, gate);
      gate = fmaf(hv.y, w4[i].y, gate);
      gate = fmaf(hv.z, w4[i].z, gate);
      gate = fmaf(hv.w, w4[i].w, gate);
    }
    lg[g] = gate;
    __syncthreads();
    if (g < HD){
      float iv = sigm(lg[g]);
      float fv = sigm(lg[HD+g]);
      float gv = tanh_fast(lg[2*HD+g]);
      float ov = sigm(lg[3*HD+g]);
      c = fmaf(fv, c, iv*gv);
      float h = ov * tanh_fast(c);
      lh[g] = h;
      // half index: ((n*TP + t/2)*HD + g)*2 + (t&1)
      h_all[(((size_t)n*TP + (t>>1))*HD + g)*2 + (t&1)] = __float2half(h);
    }
    __syncthreads();
  }
}

// ---- phase B: gconv layer. wave per (node, t-half): 12 t's = 6 half2 pairs in registers ----
// lane = channel. Gather fp16 features, fp32 accumulate, shfl-broadcast GEMV, relu, store fp16.
__global__ __launch_bounds__(256) void gconv_mid_kernel(const __half2* __restrict__ src_feat, __half2* __restrict__ dst_feat,
                                                        const float* __restrict__ Wg, const float* __restrict__ bg,
                                                        const int* __restrict__ csr_off, const int2* __restrict__ csr_pk,
                                                        const float* __restrict__ norm_dst){
  int wid = blockIdx.x*4 + (threadIdx.x >> 6);
  int lane = threadIdx.x & 63;
  if (wid >= NN*2) return;
  int n  = wid >> 1;
  int hf = wid & 1;
  const int tpo = hf*6;

  float wcol[HD];
  #pragma unroll
  for (int k=0;k<HD;k++) wcol[k] = Wg[k*HD + lane];
  float bias = bg[lane];

  float2 acc[6];
  #pragma unroll
  for (int j=0;j<6;j++) acc[j] = make_float2(0.f, 0.f);

  int e = csr_off[n];
  const int end = csr_off[n+1];
  for (; e+1 < end; e += 2){
    int2 p0 = csr_pk[e];
    int2 p1 = csr_pk[e+1];
    float w0 = __int_as_float(p0.y);
    float w1 = __int_as_float(p1.y);
    const __half2* b0 = src_feat + (size_t)p0.x*(TP*HD) + tpo*HD + lane;
    const __half2* b1 = src_feat + (size_t)p1.x*(TP*HD) + tpo*HD + lane;
    __half2 u0[6], u1[6];
    #pragma unroll
    for (int j=0;j<6;j++) u0[j] = b0[j*HD];
    #pragma unroll
    for (int j=0;j<6;j++) u1[j] = b1[j*HD];
    #pragma unroll
    for (int j=0;j<6;j++){
      float2 f0 = __half22float2(u0[j]);
      float2 f1 = __half22float2(u1[j]);
      acc[j].x = fmaf(w0, f0.x, acc[j].x);
      acc[j].y = fmaf(w0, f0.y, acc[j].y);
      acc[j].x = fmaf(w1, f1.x, acc[j].x);
      acc[j].y = fmaf(w1, f1.y, acc[j].y);
    }
  }
  if (e < end){
    int2 p0 = csr_pk[e];
    float w0 = __int_as_float(p0.y);
    const __half2* b0 = src_feat + (size_t)p0.x*(TP*HD) + tpo*HD + lane;
    #pragma unroll
    for (int j=0;j<6;j++){
      float2 f0 = __half22float2(b0[j*HD]);
      acc[j].x = fmaf(w0, f0.x, acc[j].x);
      acc[j].y = fmaf(w0, f0.y, acc[j].y);
    }
  }
  float nd = norm_dst[n];
  #pragma unroll
  for (int j=0;j<6;j++){ acc[j].x *= nd; acc[j].y *= nd; }

  __half2* dbase = dst_feat + (size_t)n*(TP*HD) + tpo*HD + lane;
  #pragma unroll
  for (int j=0;j<6;j++){
    float oe = bias, oo = bias;
    #pragma unroll
    for (int k=0;k<HD;k++){
      float ae = __shfl(acc[j].x, k, 64);
      float ao = __shfl(acc[j].y, k, 64);
      oe = fmaf(ae, wcol[k], oe);
      oo = fmaf(ao, wcol[k], oo);
    }
    oe = fmaxf(oe, 0.0f);
    oo = fmaxf(oo, 0.0f);
    dbase[j*HD] = __floats2half2_rn(oe, oo);
  }
}

// ---- phase B: last hidden gconv fused with 64->1 projection ----
__global__ __launch_bounds__(256) void gconv_last_kernel(const __half2* __restrict__ src_feat, float* __restrict__ q,
                                                         const float* __restrict__ Wg, const float* __restrict__ bg,
                                                         const float* __restrict__ Wg2,
                                                         const int* __restrict__ csr_off, const int2* __restrict__ csr_pk,
                                                         const float* __restrict__ norm_dst, const float* __restrict__ norm_src){
  int wid = blockIdx.x*4 + (threadIdx.x >> 6);
  int lane = threadIdx.x & 63;
  if (wid >= NN*2) return;
  int n  = wid >> 1;
  int hf = wid & 1;
  const int tpo = hf*6;

  float wcol[HD];
  #pragma unroll
  for (int k=0;k<HD;k++) wcol[k] = Wg[k*HD + lane];
  float bias = bg[lane];
  float w2 = Wg2[lane];

  float2 acc[6];
  #pragma unroll
  for (int j=0;j<6;j++) acc[j] = make_float2(0.f, 0.f);

  int e = csr_off[n];
  const int end = csr_off[n+1];
  for (; e+1 < end; e += 2){
    int2 p0 = csr_pk[e];
    int2 p1 = csr_pk[e+1];
    float w0 = __int_as_float(p0.y);
    float w1 = __int_as_float(p1.y);
    const __half2* b0 = src_feat + (size_t)p0.x*(TP*HD) + tpo*HD + lane;
    const __half2* b1 = src_feat + (size_t)p1.x*(TP*HD) + tpo*HD + lane;
    __half2 u0[6], u1[6];
    #pragma unroll
    for (int j=0;j<6;j++) u0[j] = b0[j*HD];
    #pragma unroll
    for (int j=0;j<6;j++) u1[j] = b1[j*HD];
    #pragma unroll
    for (int j=0;j<6;j++){
      float2 f0 = __half22float2(u0[j]);
      float2 f1 = __half22float2(u1[j]);
      acc[j].x = fmaf(w0, f0.x, acc[j].x);
      acc[j].y = fmaf(w0, f0.y, acc[j].y);
      acc[j].x = fmaf(w1, f1.x, acc[j].x);
      acc[j].y = fmaf(w1, f1.y, acc[j].y);
    }
  }
  if (e < end){
    int2 p0 = csr_pk[e];
    float w0 = __int_as_float(p0.y);
    const __half2* b0 = src_feat + (size_t)p0.x*(TP*HD) + tpo*HD + lane;
    #pragma unroll
    for (int j=0;j<6;j++){
      float2 f0 = __half22float2(b0[j*HD]);
      acc[j].x = fmaf(w0, f0.x, acc[j].x);
      acc[j].y = fmaf(w0, f0.y, acc[j].y);
    }
  }
  float nd = norm_dst[n];
  #pragma unroll
  for (int j=0;j<6;j++){ acc[j].x *= nd; acc[j].y *= nd; }

  float ns = norm_src[n];
  #pragma unroll
  for (int j=0;j<6;j++){
    float oe = bias, oo = bias;
    #pragma unroll
    for (int k=0;k<HD;k++){
      float ae = __shfl(acc[j].x, k, 64);
      float ao = __shfl(acc[j].y, k, 64);
      oe = fmaf(ae, wcol[k], oe);
      oo = fmaf(ao, wcol[k], oo);
    }
    oe = fmaxf(oe, 0.0f) * w2;
    oo = fmaxf(oo, 0.0f) * w2;
    #pragma unroll
    for (int off=32; off; off >>= 1){
      oe += __shfl_xor(oe, off, 64);
      oo += __shfl_xor(oo, off, 64);
    }
    if (lane == 0){
      int tp = tpo + j;
      q[n*32 + 2*tp]     = oe * ns;
      q[n*32 + 2*tp + 1] = oo * ns;
    }
  }
}

// ---- phase B: final scalar aggregation -> output (N,T). Full wave: 2 edges/iter via halves ----
__global__ __launch_bounds__(256) void out_kernel(const float* __restrict__ q, const int* __restrict__ csr_off,
                                                  const int2* __restrict__ csr_pk, const float* __restrict__ norm_dst,
                                                  const float* __restrict__ bg2, float* __restrict__ out){
  int n = blockIdx.x*4 + (threadIdx.x >> 6);
  int lane = threadIdx.x & 63;
  if (n >= NN) return;
  int sub = lane >> 5;        // 0: even edge, 1: odd edge
  int tl  = lane & 31;        // timestep (0..23 active)
  bool act = tl < TT;
  int e = csr_off[n];
  const int end = csr_off[n+1];
  float s0 = 0.f, s1 = 0.f;
  for (; e+3 < end; e += 4){
    int a = csr_pk[e+sub].x;
    int b = csr_pk[e+2+sub].x;
    if (act){
      s0 += q[a*32 + tl];
      s1 += q[b*32 + tl];
    }
  }
  for (; e+1 < end; e += 2){
    int a = csr_pk[e+sub].x;
    if (act) s0 += q[a*32 + tl];
  }
  if (e < end && sub == 0 && act) s1 += q[csr_pk[e].x*32 + tl];
  float s = s0 + s1;
  s += __shfl_xor(s, 32, 64);
  if (sub == 0 && act) out[n*TT + tl] = fmaf(norm_dst[n], s, bg2[0]);
}

extern "C" void kernel_launch(void* const* d_in, const int* in_sizes, int n_in,
                              void* d_out, int out_size, void* d_ws, size_t ws_size,
                              hipStream_t stream) {
  (void)in_sizes; (void)n_in; (void)out_size; (void)ws_size;
  const float* blob  = (const float*)d_in[0];
  const float* W_ih  = (const float*)d_in[1];
  const float* b_ih  = (const float*)d_in[2];
  const float* W_hh  = (const float*)d_in[3];
  const float* b_hh  = (const float*)d_in[4];
  const float* Wg0   = (const float*)d_in[5];
  const float* bg0   = (const float*)d_in[6];
  const float* Wg1   = (const float*)d_in[7];
  const float* bg1   = (const float*)d_in[8];
  const float* Wg2   = (const float*)d_in[9];
  const float* bg2   = (const float*)d_in[10];
  const int* edge_src = (const int*)d_in[11];
  const int* edge_dst = (const int*)d_in[12];
  float* out = (float*)d_out;

  char* ws = (char*)d_ws;
  size_t off = 0;
  auto alloc = [&](size_t bytes)->char* {
    char* p = ws + off; off += (bytes + 255) & ~(size_t)255; return p;
  };
  __half* h_all   = (__half*)alloc((size_t)NN*TT*HD*sizeof(__half));  // 30.7 MB, [n][tp][ch] half2-packed
  __half* z1      = (__half*)alloc((size_t)NN*TT*HD*sizeof(__half));  // 30.7 MB
  float*  q       = (float*) alloc((size_t)NN*32*sizeof(float));      // 1.28 MB
  int*    deg_out = (int*)   alloc((size_t)NN*sizeof(int));
  int*    deg_in  = (int*)   alloc((size_t)NN*sizeof(int));
  float*  norm_src= (float*) alloc((size_t)NN*sizeof(float));
  float*  norm_dst= (float*) alloc((size_t)NN*sizeof(float));
  int*    csr_off = (int*)   alloc((size_t)(NN+1)*sizeof(int));
  int*    cursor  = (int*)   alloc((size_t)NN*sizeof(int));
  int2*   csr_pk  = (int2*)  alloc((size_t)NE*sizeof(int2));          // 2.56 MB

  hipMemsetAsync(deg_out, 0, (size_t)NN*sizeof(int), stream);
  hipMemsetAsync(deg_in,  0, (size_t)NN*sizeof(int), stream);

  degree_kernel<<<(NE+255)/256, 256, 0, stream>>>(edge_src, edge_dst, deg_out, deg_in);
  norm_kernel<<<(NN+255)/256, 256, 0, stream>>>(deg_out, deg_in, norm_src, norm_dst);
  scan_kernel<<<1, 256, 0, stream>>>(deg_in, csr_off, cursor);
  fill_kernel<<<(NE+255)/256, 256, 0, stream>>>(edge_src, edge_dst, cursor, csr_pk, norm_src);

  lstm_kernel<<<NN, 256, 0, stream>>>(blob, W_ih, b_ih, W_hh, b_hh, h_all);

  gconv_mid_kernel<<<(NN*2+3)/4, 256, 0, stream>>>((const __half2*)h_all, (__half2*)z1, Wg0, bg0,
                                                   csr_off, csr_pk, norm_dst);
  gconv_last_kernel<<<(NN*2+3)/4, 256, 0, stream>>>((const __half2*)z1, q, Wg1, bg1, Wg2,
                                                    csr_off, csr_pk, norm_dst, norm_src);
  out_kernel<<<(NN+3)/4, 256, 0, stream>>>(q, csr_off, csr_pk, norm_dst, bg2, out);
}